// Round 19
// baseline (216.022 us; speedup 1.0000x reference)
//
#include <hip/hip_runtime.h>
#include <hip/hip_bf16.h>

// FSMNSeleNetV3 — round 19: unit0_big no-spill at 4 blocks/CU.
//   Ledger: r16 (256,4) spilled 14 MB (arch half of the 128-reg cap too small
//   for bE[2][4]+a[5]) but kept 4 blocks -> 209.4 (best). r17/r18 fixed the
//   spill but lost occupancy -> 219/214. Fix: keep (256,4) AND shrink expand's
//   peak arch set: per-mt single fragment read consumed immediately by both
//   nt MFMAs (arch ~51 < 64; accE stays AGPR) — the same structure shrink
//   already uses. LDS read count unchanged.
//   unit14_big / final / prep unchanged.
// d_ws: H0 (33.5MB) + H1 (33.5MB) + wbuf (192KB bf16 weights) + WdT (2.5KB f32).

#define TLEN 2048
#define SEQS 128

typedef __attribute__((ext_vector_type(8))) short bf16x8;
typedef __attribute__((ext_vector_type(4))) float f32x4;
typedef __attribute__((ext_vector_type(2))) float f32x2;

__device__ __forceinline__ ushort f2b(float f) {
    unsigned u = __builtin_bit_cast(unsigned, f);
    return (ushort)((u + 0x7fffu + ((u >> 16) & 1u)) >> 16);  // RNE
}
__device__ __forceinline__ float b2f(ushort u) {
    unsigned v = ((unsigned)u) << 16;
    return __builtin_bit_cast(float, v);
}
__device__ __forceinline__ unsigned cvtpk(float lo, float hi) {  // RNE pack
    unsigned r;
    asm("v_cvt_pk_bf16_f32 %0, %1, %2" : "=v"(r) : "v"(lo), "v"(hi));
    return r;
}
__device__ __forceinline__ f32x2 pkfma(f32x2 a, f32x2 b, f32x2 c) {
    f32x2 d;
    asm("v_pk_fma_f32 %0, %1, %2, %3" : "=v"(d) : "v"(a), "v"(b), "v"(c));
    return d;
}
__device__ __forceinline__ void gload16(void* lds, const void* g) {
    __builtin_amdgcn_global_load_lds(
        (const __attribute__((address_space(1))) unsigned*)g,
        (__attribute__((address_space(3))) unsigned*)lds, 16, 0, 0);
}

// storage k' -> source k for the E pair-packing permutation:
// k' = 32a + 2r + nb  <->  k = 32a + 16nb + r
__device__ __forceinline__ int kperm(int kp) {
    return (kp & ~31) | ((kp & 1) << 4) | ((kp & 31) >> 1);
}

// ---- weight prep (unchanged) ----
__global__ __launch_bounds__(256) void prep_k(
    const float* __restrict__ We0, const float* __restrict__ Ws0,
    const float* __restrict__ We,  const float* __restrict__ Ws,
    const float* __restrict__ We2, const float* __restrict__ Wd,
    ushort* __restrict__ wbuf, float* __restrict__ wdtf)
{
    int idx = blockIdx.x * 256 + threadIdx.x;
    if (idx >= 98944) return;
    if (idx >= 98304) {
        int i = idx - 98304;
        wdtf[i] = Wd[(i & 127) * 5 + (i >> 7)];
        return;
    }
    float v;
    if (idx < 16384) {
        int n = idx >> 7, k = idx & 127;
        v = (k < 120) ? We0[k * 128 + n] : 0.f;
    } else if (idx < 24576) {
        int i = idx - 16384;
        int n = i >> 7, k = kperm(i & 127);
        v = Ws0[k * 64 + n];
    } else if (idx < 90112) {
        int i = idx - 24576;
        int l = i >> 14, j = i & 16383;
        if (j < 8192) { int n = j >> 6, k = j & 63; v = We[l * 8192 + k * 128 + n]; }
        else { int j2 = j - 8192; int n = j2 >> 7, k = kperm(j2 & 127); v = Ws[l * 8192 + k * 64 + n]; }
    } else {
        int i = idx - 90112;
        int n = i >> 6, k = i & 63;
        v = We2[k * 128 + n];
    }
    wbuf[idx] = f2b(v);
}

// ---- unit 0: 128-row straight-line, single-region X->E->Z per-row alias ----
// LDS: one region [139][256B] = 35584 B -> 4 blocks/CU.
__global__ __launch_bounds__(256, 4) void unit0_big(
    const float* __restrict__ in, const ushort* __restrict__ WeT,
    const float* __restrict__ be, const ushort* __restrict__ WsT,
    const float* __restrict__ wl, const float* __restrict__ wr,
    ushort* __restrict__ Hout)
{
    __shared__ char smA[139 * 256];

    const int tid = threadIdx.x;
    const int s   = blockIdx.y;
    const int t0  = blockIdx.x * 128;
    const int ln  = tid & 63;
    const int w   = tid >> 6;
    const int lr  = ln & 15;
    const int lg  = ln >> 4;

    // ---- stage X rows 0..138 (t = t0-10+row); invalid/pad slots write zero ----
    {
        const int bq = s >> 2, cq = s & 3;
        for (int i = tid; i < 139 * 16; i += 256) {
            int r = i >> 4, s16 = i & 15;
            int t = t0 - 10 + r;
            float4 v0 = make_float4(0.f, 0.f, 0.f, 0.f), v1 = v0;
            if (t >= 0 && t < TLEN && s16 < 15) {
                int fb = ((bq * TLEN + t) * 4 + cq) * 120 + s16 * 8;
                v0 = *reinterpret_cast<const float4*>(in + fb);
                v1 = *reinterpret_cast<const float4*>(in + fb + 4);
            }
            uint4 p;
            p.x = cvtpk(v0.x, v0.y); p.y = cvtpk(v0.z, v0.w);
            p.z = cvtpk(v1.x, v1.y); p.w = cvtpk(v1.z, v1.w);
            int off = (r * 256 + s16 * 16) ^ ((r & 15) << 4);
            *reinterpret_cast<uint4*>(smA + off) = p;
        }
    }
    __syncthreads();

    // ---- expand half A: mt 0..4 (X rows 0..79); per-mt fragment read ----
    {
        bf16x8 bE[2][4];
#pragma unroll
        for (int nt = 0; nt < 2; ++nt)
#pragma unroll
            for (int kc = 0; kc < 4; ++kc) {
                int n = w * 32 + nt * 16 + lr;
                bE[nt][kc] = *reinterpret_cast<const bf16x8*>(
                    WeT + n * 128 + kc * 32 + lg * 8);
            }
        f32x4 accE[5][2];
#pragma unroll
        for (int mt = 0; mt < 5; ++mt)
#pragma unroll
            for (int nt = 0; nt < 2; ++nt) accE[mt][nt] = (f32x4){0.f, 0.f, 0.f, 0.f};
        __builtin_amdgcn_s_setprio(1);
#pragma unroll
        for (int kc = 0; kc < 4; ++kc)
#pragma unroll
            for (int mt = 0; mt < 5; ++mt) {
                int row = mt * 16 + lr;
                int off = (row * 256 + kc * 64 + lg * 16) ^ ((row & 15) << 4);
                bf16x8 a = *reinterpret_cast<const bf16x8*>(smA + off);
                accE[mt][0] = __builtin_amdgcn_mfma_f32_16x16x32_bf16(
                    a, bE[0][kc], accE[mt][0], 0, 0, 0);
                accE[mt][1] = __builtin_amdgcn_mfma_f32_16x16x32_bf16(
                    a, bE[1][kc], accE[mt][1], 0, 0, 0);
            }
        __builtin_amdgcn_s_setprio(0);
        __syncthreads();   // ALL waves done reading X rows 0..79
        float b0 = be[w * 32 + lr];
        float b1 = be[w * 32 + 16 + lr];
        // E rows 0..79 overwrite X rows 0..79 (per-row alias)
#pragma unroll
        for (int mt = 0; mt < 5; ++mt)
#pragma unroll
            for (int q = 0; q < 4; ++q) {
                int row = mt * 16 + lg * 4 + q;
                float v0 = fmaxf(accE[mt][0][q] + b0, 0.f);
                float v1 = fmaxf(accE[mt][1][q] + b1, 0.f);
                int off = (row * 256 + w * 64 + lr * 4) ^ ((row & 15) << 4);
                *reinterpret_cast<unsigned*>(smA + off) = cvtpk(v0, v1);
            }
    }

    // ---- expand half B: mt 5..8 (X rows 80..138; guard <139) ----
    {
        bf16x8 bE[2][4];
#pragma unroll
        for (int nt = 0; nt < 2; ++nt)
#pragma unroll
            for (int kc = 0; kc < 4; ++kc) {
                int n = w * 32 + nt * 16 + lr;
                bE[nt][kc] = *reinterpret_cast<const bf16x8*>(
                    WeT + n * 128 + kc * 32 + lg * 8);
            }
        f32x4 accE[4][2];
#pragma unroll
        for (int mt = 0; mt < 4; ++mt)
#pragma unroll
            for (int nt = 0; nt < 2; ++nt) accE[mt][nt] = (f32x4){0.f, 0.f, 0.f, 0.f};
        bf16x8 zv = {0, 0, 0, 0, 0, 0, 0, 0};
        __builtin_amdgcn_s_setprio(1);
#pragma unroll
        for (int kc = 0; kc < 4; ++kc)
#pragma unroll
            for (int mtl = 0; mtl < 4; ++mtl) {
                int row = (5 + mtl) * 16 + lr;
                int off = (row * 256 + kc * 64 + lg * 16) ^ ((row & 15) << 4);
                bf16x8 a = (row < 139) ? *reinterpret_cast<const bf16x8*>(smA + off) : zv;
                accE[mtl][0] = __builtin_amdgcn_mfma_f32_16x16x32_bf16(
                    a, bE[0][kc], accE[mtl][0], 0, 0, 0);
                accE[mtl][1] = __builtin_amdgcn_mfma_f32_16x16x32_bf16(
                    a, bE[1][kc], accE[mtl][1], 0, 0, 0);
            }
        __builtin_amdgcn_s_setprio(0);
        __syncthreads();   // ALL waves done reading X rows 80..138
        float b0 = be[w * 32 + lr];
        float b1 = be[w * 32 + 16 + lr];
#pragma unroll
        for (int mtl = 0; mtl < 4; ++mtl)
#pragma unroll
            for (int q = 0; q < 4; ++q) {
                int row = (5 + mtl) * 16 + lg * 4 + q;
                if (row < 139) {
                    float v0 = fmaxf(accE[mtl][0][q] + b0, 0.f);
                    float v1 = fmaxf(accE[mtl][1][q] + b1, 0.f);
                    int off = (row * 256 + w * 64 + lr * 4) ^ ((row & 15) << 4);
                    *reinterpret_cast<unsigned*>(smA + off) = cvtpk(v0, v1);
                }
            }
    }
    __syncthreads();   // all E visible

    // ---- shrink: Z[139][64] = E @ WsT_perm; wave w: cols w*16..+16 ----
    {
        bf16x8 bS[4];
#pragma unroll
        for (int kc = 0; kc < 4; ++kc) {
            int n = w * 16 + lr;
            bS[kc] = *reinterpret_cast<const bf16x8*>(WsT + n * 128 + kc * 32 + lg * 8);
        }
        f32x4 accS[9];
#pragma unroll
        for (int mt = 0; mt < 9; ++mt) accS[mt] = (f32x4){0.f, 0.f, 0.f, 0.f};
        bf16x8 zv = {0, 0, 0, 0, 0, 0, 0, 0};
        __builtin_amdgcn_s_setprio(1);
#pragma unroll
        for (int kc = 0; kc < 4; ++kc) {
#pragma unroll
            for (int mt = 0; mt < 8; ++mt) {
                int row = mt * 16 + lr;
                int off = (row * 256 + kc * 64 + lg * 16) ^ ((row & 15) << 4);
                bf16x8 a = *reinterpret_cast<const bf16x8*>(smA + off);
                accS[mt] = __builtin_amdgcn_mfma_f32_16x16x32_bf16(
                    a, bS[kc], accS[mt], 0, 0, 0);
            }
            {   // mt = 8 guarded
                int row = 128 + lr;
                int off = (row * 256 + kc * 64 + lg * 16) ^ ((row & 15) << 4);
                bf16x8 a = (row < 139) ? *reinterpret_cast<const bf16x8*>(smA + off) : zv;
                accS[8] = __builtin_amdgcn_mfma_f32_16x16x32_bf16(
                    a, bS[kc], accS[8], 0, 0, 0);
            }
        }
        __builtin_amdgcn_s_setprio(0);
        __syncthreads();   // all E reads done (Z aliases per-row)
#pragma unroll
        for (int mt = 0; mt < 9; ++mt)
#pragma unroll
            for (int q = 0; q < 4; ++q) {
                int row = mt * 16 + lg * 4 + q;
                if (row < 139) {
                    int off = (row * 256 + (w * 16 + lr) * 4) ^ ((row & 15) << 3);
                    *reinterpret_cast<float*>(smA + off) = accS[mt][q];
                }
            }
    }
    __syncthreads();

    // ---- FSMN epilogue: 2 adjacent d per thread, 16 rows each (no residual) ----
    {
        const int dp = (tid & 31) * 2;
        const int r0 = (tid >> 5) * 16;
        f32x2 wl2[10];
#pragma unroll
        for (int k = 0; k < 10; ++k)
            wl2[k] = *reinterpret_cast<const f32x2*>(wl + k * 64 + dp);
        f32x2 wr2 = *reinterpret_cast<const f32x2*>(wr + dp);

        f32x2 zw[11];
#pragma unroll
        for (int j = 0; j < 11; ++j) {
            int tt = t0 + r0 - 9 + j;
            int r  = r0 + 1 + j;
            zw[j] = (tt >= 0 && tt < TLEN)
                  ? *reinterpret_cast<const f32x2*>(
                        smA + ((r * 256 + dp * 4) ^ ((r & 15) << 3)))
                  : (f32x2){0.f, 0.f};
        }
#pragma unroll
        for (int i = 0; i < 16; ++i) {
            int ro = r0 + i, t = t0 + ro;
            f32x2 acc = zw[9];
#pragma unroll
            for (int k = 0; k < 10; ++k) acc = pkfma(wl2[k], zw[k], acc);
            acc = pkfma(wr2, zw[10], acc);
            *reinterpret_cast<unsigned*>(
                Hout + (size_t)(s * TLEN + t) * 64 + dp) = cvtpk(acc[0], acc[1]);
            if (i < 15) {
#pragma unroll
                for (int j = 0; j < 10; ++j) zw[j] = zw[j + 1];
                int tt = t + 2;
                int r  = ro + 12;
                zw[10] = (tt < TLEN)
                       ? *reinterpret_cast<const f32x2*>(
                             smA + ((r * 256 + dp * 4) ^ ((r & 15) << 3)))
                       : (f32x2){0.f, 0.f};
            }
        }
    }
}

// ---- units 1-4: 128-row straight-line tile (r15, unchanged) ----
__global__ __launch_bounds__(256, 3) void unit14_big(
    const ushort* __restrict__ Hin, const ushort* __restrict__ WeT,
    const float* __restrict__ be, const ushort* __restrict__ WsT,
    const float* __restrict__ wl, const float* __restrict__ wr,
    ushort* __restrict__ Hout)
{
    __shared__ char smraw[17792 + 35584];
    char* smA = smraw;
    char* smB = smraw + 17792;

    const int tid = threadIdx.x;
    const int s   = blockIdx.y;
    const int t0  = blockIdx.x * 128;
    const int ln  = tid & 63;
    const int w   = tid >> 6;
    const int lr  = ln & 15;
    const int lg  = ln >> 4;

    {
        bf16x8 zv = {0, 0, 0, 0, 0, 0, 0, 0};
        if (t0 == 0)
            for (int i = tid; i < 80; i += 256)
                *reinterpret_cast<bf16x8*>(smA + i * 16) = zv;
        if (t0 == TLEN - 128 && tid < 8)
            *reinterpret_cast<bf16x8*>(smA + (138 * 8 + tid) * 16) = zv;
#pragma unroll
        for (int it = 0; it < 5; ++it) {
            int r0s = it * 32 + w * 8;
            if (r0s < 139) {
                int row = r0s + (ln >> 3);
                int t   = t0 - 10 + row;
                int sslot = (ln & 7) ^ (row & 7);
                if (row < 139 && t >= 0 && t < TLEN)
                    gload16(smA + r0s * 128,
                            Hin + (size_t)(s * TLEN + t) * 64 + sslot * 8);
            }
        }
    }
    __syncthreads();

    {
        bf16x8 bE[2][2];
#pragma unroll
        for (int nt = 0; nt < 2; ++nt)
#pragma unroll
            for (int kc = 0; kc < 2; ++kc) {
                int n = w * 32 + nt * 16 + lr;
                bE[nt][kc] = *reinterpret_cast<const bf16x8*>(
                    WeT + n * 64 + kc * 32 + lg * 8);
            }
        f32x4 accE[5][2];
#pragma unroll
        for (int mt = 0; mt < 5; ++mt)
#pragma unroll
            for (int nt = 0; nt < 2; ++nt) accE[mt][nt] = (f32x4){0.f, 0.f, 0.f, 0.f};
        __builtin_amdgcn_s_setprio(1);
#pragma unroll
        for (int kc = 0; kc < 2; ++kc) {
            bf16x8 a[5];
#pragma unroll
            for (int mt = 0; mt < 5; ++mt) {
                int row = mt * 16 + lr;
                int off = (row * 128 + kc * 64 + lg * 16) ^ ((row & 7) << 4);
                a[mt] = *reinterpret_cast<const bf16x8*>(smA + off);
            }
#pragma unroll
            for (int mt = 0; mt < 5; ++mt)
#pragma unroll
                for (int nt = 0; nt < 2; ++nt)
                    accE[mt][nt] = __builtin_amdgcn_mfma_f32_16x16x32_bf16(
                        a[mt], bE[nt][kc], accE[mt][nt], 0, 0, 0);
        }
        __builtin_amdgcn_s_setprio(0);
        float b0 = be[w * 32 + lr];
        float b1 = be[w * 32 + 16 + lr];
#pragma unroll
        for (int mt = 0; mt < 5; ++mt)
#pragma unroll
            for (int q = 0; q < 4; ++q) {
                int row = mt * 16 + lg * 4 + q;
                float v0 = fmaxf(accE[mt][0][q] + b0, 0.f);
                float v1 = fmaxf(accE[mt][1][q] + b1, 0.f);
                int off = (row * 256 + w * 64 + lr * 4) ^ ((row & 15) << 4);
                *reinterpret_cast<unsigned*>(smB + off) = cvtpk(v0, v1);
            }
    }
    {
        bf16x8 bE[2][2];
#pragma unroll
        for (int nt = 0; nt < 2; ++nt)
#pragma unroll
            for (int kc = 0; kc < 2; ++kc) {
                int n = w * 32 + nt * 16 + lr;
                bE[nt][kc] = *reinterpret_cast<const bf16x8*>(
                    WeT + n * 64 + kc * 32 + lg * 8);
            }
        f32x4 accE[4][2];
#pragma unroll
        for (int mt = 0; mt < 4; ++mt)
#pragma unroll
            for (int nt = 0; nt < 2; ++nt) accE[mt][nt] = (f32x4){0.f, 0.f, 0.f, 0.f};
        bf16x8 zv = {0, 0, 0, 0, 0, 0, 0, 0};
        __builtin_amdgcn_s_setprio(1);
#pragma unroll
        for (int kc = 0; kc < 2; ++kc) {
            bf16x8 a[4];
#pragma unroll
            for (int mtl = 0; mtl < 4; ++mtl) {
                int row = (5 + mtl) * 16 + lr;
                int off = (row * 128 + kc * 64 + lg * 16) ^ ((row & 7) << 4);
                a[mtl] = (row < 139) ? *reinterpret_cast<const bf16x8*>(smA + off) : zv;
            }
#pragma unroll
            for (int mtl = 0; mtl < 4; ++mtl)
#pragma unroll
                for (int nt = 0; nt < 2; ++nt)
                    accE[mtl][nt] = __builtin_amdgcn_mfma_f32_16x16x32_bf16(
                        a[mtl], bE[nt][kc], accE[mtl][nt], 0, 0, 0);
        }
        __builtin_amdgcn_s_setprio(0);
        float b0 = be[w * 32 + lr];
        float b1 = be[w * 32 + 16 + lr];
#pragma unroll
        for (int mtl = 0; mtl < 4; ++mtl)
#pragma unroll
            for (int q = 0; q < 4; ++q) {
                int row = (5 + mtl) * 16 + lg * 4 + q;
                if (row < 139) {
                    float v0 = fmaxf(accE[mtl][0][q] + b0, 0.f);
                    float v1 = fmaxf(accE[mtl][1][q] + b1, 0.f);
                    int off = (row * 256 + w * 64 + lr * 4) ^ ((row & 15) << 4);
                    *reinterpret_cast<unsigned*>(smB + off) = cvtpk(v0, v1);
                }
            }
    }
    __syncthreads();

    {
        bf16x8 bS[4];
#pragma unroll
        for (int kc = 0; kc < 4; ++kc) {
            int n = w * 16 + lr;
            bS[kc] = *reinterpret_cast<const bf16x8*>(WsT + n * 128 + kc * 32 + lg * 8);
        }
        f32x4 accS[9];
#pragma unroll
        for (int mt = 0; mt < 9; ++mt) accS[mt] = (f32x4){0.f, 0.f, 0.f, 0.f};
        bf16x8 zv = {0, 0, 0, 0, 0, 0, 0, 0};
        __builtin_amdgcn_s_setprio(1);
#pragma unroll
        for (int kc = 0; kc < 4; ++kc) {
#pragma unroll
            for (int mt = 0; mt < 8; ++mt) {
                int row = mt * 16 + lr;
                int off = (row * 256 + kc * 64 + lg * 16) ^ ((row & 15) << 4);
                bf16x8 a = *reinterpret_cast<const bf16x8*>(smB + off);
                accS[mt] = __builtin_amdgcn_mfma_f32_16x16x32_bf16(
                    a, bS[kc], accS[mt], 0, 0, 0);
            }
            {
                int row = 128 + lr;
                int off = (row * 256 + kc * 64 + lg * 16) ^ ((row & 15) << 4);
                bf16x8 a = (row < 139) ? *reinterpret_cast<const bf16x8*>(smB + off) : zv;
                accS[8] = __builtin_amdgcn_mfma_f32_16x16x32_bf16(
                    a, bS[kc], accS[8], 0, 0, 0);
            }
        }
        __builtin_amdgcn_s_setprio(0);
        __syncthreads();
#pragma unroll
        for (int mt = 0; mt < 9; ++mt)
#pragma unroll
            for (int q = 0; q < 4; ++q) {
                int row = mt * 16 + lg * 4 + q;
                if (row < 139) {
                    int off = (row * 256 + (w * 16 + lr) * 4) ^ ((row & 15) << 3);
                    *reinterpret_cast<float*>(smB + off) = accS[mt][q];
                }
            }
    }
    __syncthreads();

    {
        const int dp = (tid & 31) * 2;
        const int r0 = (tid >> 5) * 16;
        f32x2 wl2[10];
#pragma unroll
        for (int k = 0; k < 10; ++k)
            wl2[k] = *reinterpret_cast<const f32x2*>(wl + k * 64 + dp);
        f32x2 wr2 = *reinterpret_cast<const f32x2*>(wr + dp);

        f32x2 zw[11];
#pragma unroll
        for (int j = 0; j < 11; ++j) {
            int tt = t0 + r0 - 9 + j;
            int r  = r0 + 1 + j;
            zw[j] = (tt >= 0 && tt < TLEN)
                  ? *reinterpret_cast<const f32x2*>(
                        smB + ((r * 256 + dp * 4) ^ ((r & 15) << 3)))
                  : (f32x2){0.f, 0.f};
        }
#pragma unroll
        for (int i = 0; i < 16; ++i) {
            int ro = r0 + i, t = t0 + ro;
            f32x2 acc = zw[9];
#pragma unroll
            for (int k = 0; k < 10; ++k) acc = pkfma(wl2[k], zw[k], acc);
            acc = pkfma(wr2, zw[10], acc);
            int rowX = ro + 10;
            ushort2 h = *reinterpret_cast<const ushort2*>(
                smA + ((rowX * 128 + dp * 2) ^ ((rowX & 7) << 4)));
            float a0 = acc[0] + b2f(h.x);
            float a1 = acc[1] + b2f(h.y);
            *reinterpret_cast<unsigned*>(
                Hout + (size_t)(s * TLEN + t) * 64 + dp) = cvtpk(a0, a1);
            if (i < 15) {
#pragma unroll
                for (int j = 0; j < 10; ++j) zw[j] = zw[j + 1];
                int tt = t + 2;
                int r  = ro + 12;
                zw[10] = (tt < TLEN)
                       ? *reinterpret_cast<const f32x2*>(
                             smB + ((r * 256 + dp * 4) ^ ((r & 15) << 3)))
                       : (f32x2){0.f, 0.f};
            }
        }
    }
}

// ---- final (unchanged) ----
__global__ __launch_bounds__(256) void final_mfma(
    const ushort* __restrict__ H, const ushort* __restrict__ We2T,
    const float* __restrict__ be2, const float* __restrict__ WdT,
    const float* __restrict__ bd, float* __restrict__ out)
{
    __shared__ char smA[64 * 128];
    __shared__ float Ml[16][132];
    const int tid = threadIdx.x;
    const int ln  = tid & 63;
    const int w   = tid >> 6;
    const int lr  = ln & 15;
    const int lg  = ln >> 4;
    const int b   = blockIdx.x >> 7;
    const int t0  = (blockIdx.x & 127) * 16;

#pragma unroll
    for (int it = 0; it < 2; ++it) {
        int r0 = w * 16 + it * 8;
        int tl = it * 8 + (ln >> 3);
        int m  = r0 + (ln >> 3);
        int sslot = (ln & 7) ^ (m & 7);
        gload16(smA + r0 * 128,
                H + (size_t)((b * 4 + w) * TLEN + t0 + tl) * 64 + sslot * 8);
    }
    __syncthreads();

    {
        bf16x8 bW[2][2];
#pragma unroll
        for (int nt = 0; nt < 2; ++nt)
#pragma unroll
            for (int kc = 0; kc < 2; ++kc) {
                int n = w * 32 + nt * 16 + lr;
                bW[nt][kc] = *reinterpret_cast<const bf16x8*>(
                    We2T + n * 64 + kc * 32 + lg * 8);
            }
        f32x4 acc[4][2];
#pragma unroll
        for (int mt = 0; mt < 4; ++mt)
#pragma unroll
            for (int nt = 0; nt < 2; ++nt) acc[mt][nt] = (f32x4){0.f, 0.f, 0.f, 0.f};
        __builtin_amdgcn_s_setprio(1);
#pragma unroll
        for (int kc = 0; kc < 2; ++kc) {
            bf16x8 a[4];
#pragma unroll
            for (int mt = 0; mt < 4; ++mt) {
                int m = mt * 16 + lr;
                int off = (m * 128 + kc * 64 + lg * 16) ^ ((m & 7) << 4);
                a[mt] = *reinterpret_cast<const bf16x8*>(smA + off);
            }
#pragma unroll
            for (int mt = 0; mt < 4; ++mt)
#pragma unroll
                for (int nt = 0; nt < 2; ++nt)
                    acc[mt][nt] = __builtin_amdgcn_mfma_f32_16x16x32_bf16(
                        a[mt], bW[nt][kc], acc[mt][nt], 0, 0, 0);
        }
        __builtin_amdgcn_s_setprio(0);
#pragma unroll
        for (int nt = 0; nt < 2; ++nt) {
            float bb = be2[w * 32 + nt * 16 + lr];
#pragma unroll
            for (int q = 0; q < 4; ++q) {
                float m01 = fmaxf(acc[0][nt][q], acc[1][nt][q]);
                float m23 = fmaxf(acc[2][nt][q], acc[3][nt][q]);
                Ml[lg * 4 + q][w * 32 + nt * 16 + lr] =
                    fmaxf(fmaxf(m01, m23) + bb, 0.f);
            }
        }
    }
    __syncthreads();

    if (tid < 80) {
        int t = tid / 5, q = tid - t * 5;
        const float4* wq = reinterpret_cast<const float4*>(WdT + q * 128);
        const float4* mq = reinterpret_cast<const float4*>(&Ml[t][0]);
        float s0 = 0.f, s1 = 0.f, s2 = 0.f, s3 = 0.f;
#pragma unroll 4
        for (int j = 0; j < 32; ++j) {
            float4 m = mq[j], wv = wq[j];
            s0 += m.x * wv.x; s1 += m.y * wv.y;
            s2 += m.z * wv.z; s3 += m.w * wv.w;
        }
        out[(size_t)(b * TLEN + t0 + t) * 5 + q] = s0 + s1 + s2 + s3 + bd[q];
    }
}

extern "C" void kernel_launch(void* const* d_in, const int* in_sizes, int n_in,
                              void* d_out, int out_size, void* d_ws, size_t ws_size,
                              hipStream_t stream) {
    const float* x   = (const float*)d_in[0];
    const float* We0 = (const float*)d_in[1];
    const float* be0 = (const float*)d_in[2];
    const float* Ws0 = (const float*)d_in[3];
    const float* wl0 = (const float*)d_in[4];
    const float* wr0 = (const float*)d_in[5];
    const float* We  = (const float*)d_in[6];
    const float* be  = (const float*)d_in[7];
    const float* Ws  = (const float*)d_in[8];
    const float* wl  = (const float*)d_in[9];
    const float* wr  = (const float*)d_in[10];
    const float* We2 = (const float*)d_in[11];
    const float* be2 = (const float*)d_in[12];
    const float* Wd  = (const float*)d_in[13];
    const float* bd  = (const float*)d_in[14];

    ushort* H0 = (ushort*)d_ws;                               // 33.5 MB
    ushort* H1 = H0 + (size_t)SEQS * TLEN * 64;               // 33.5 MB
    ushort* wbuf = H1 + (size_t)SEQS * TLEN * 64;             // 192 KB
    float* wdtf = (float*)(wbuf + 98304);                     // 2.5 KB

    prep_k<<<387, 256, 0, stream>>>(We0, Ws0, We, Ws, We2, Wd, wbuf, wdtf);

    unit0_big<<<dim3(TLEN / 128, SEQS), 256, 0, stream>>>(
        x, wbuf, be0, wbuf + 16384, wl0, wr0, H0);

    ushort* cur = H0;
    ushort* nxt = H1;
    for (int l = 0; l < 4; ++l) {
        const ushort* WeTl = wbuf + 24576 + l * 16384;
        const ushort* WsTl = WeTl + 8192;
        unit14_big<<<dim3(TLEN / 128, SEQS), 256, 0, stream>>>(
            cur, WeTl, be + l * 128, WsTl, wl + l * 640, wr + l * 64, nxt);
        ushort* tmp = cur; cur = nxt; nxt = tmp;
    }
    // after 4 swaps cur == H0

    final_mfma<<<32 * 128, 256, 0, stream>>>(cur, wbuf + 90112, be2, wdtf, bd,
                                             (float*)d_out);
}

// Round 20
// 210.397 us; speedup vs baseline: 1.0267x; 1.0267x over previous
//
#include <hip/hip_runtime.h>
#include <hip/hip_bf16.h>

// FSMNSeleNetV3 — round 20: restore r16 (best, 209.4 us) exactly.
//   unit0_big ledger: r16 (256,4)+batched-a[5] = 209.4 (7-reg spill, 4 blk/CU)
//   beats r17 (no bounds, 21% occ) = 219.3, r18 ((256,3), 28% occ) = 214.4,
//   r19 ((256,4)+per-mt, spill persists) = 216.0. Occupancy dominates the
//   small latency-hidden spill; allocator arch/acc split not steerable from
//   source (4 attempts). unit0_big reverted to r16 codegen verbatim.
//   unit14_big (r15) / final / prep unchanged.
// d_ws: H0 (33.5MB) + H1 (33.5MB) + wbuf (192KB bf16 weights) + WdT (2.5KB f32).

#define TLEN 2048
#define SEQS 128

typedef __attribute__((ext_vector_type(8))) short bf16x8;
typedef __attribute__((ext_vector_type(4))) float f32x4;
typedef __attribute__((ext_vector_type(2))) float f32x2;

__device__ __forceinline__ ushort f2b(float f) {
    unsigned u = __builtin_bit_cast(unsigned, f);
    return (ushort)((u + 0x7fffu + ((u >> 16) & 1u)) >> 16);  // RNE
}
__device__ __forceinline__ float b2f(ushort u) {
    unsigned v = ((unsigned)u) << 16;
    return __builtin_bit_cast(float, v);
}
__device__ __forceinline__ unsigned cvtpk(float lo, float hi) {  // RNE pack
    unsigned r;
    asm("v_cvt_pk_bf16_f32 %0, %1, %2" : "=v"(r) : "v"(lo), "v"(hi));
    return r;
}
__device__ __forceinline__ f32x2 pkfma(f32x2 a, f32x2 b, f32x2 c) {
    f32x2 d;
    asm("v_pk_fma_f32 %0, %1, %2, %3" : "=v"(d) : "v"(a), "v"(b), "v"(c));
    return d;
}
__device__ __forceinline__ void gload16(void* lds, const void* g) {
    __builtin_amdgcn_global_load_lds(
        (const __attribute__((address_space(1))) unsigned*)g,
        (__attribute__((address_space(3))) unsigned*)lds, 16, 0, 0);
}

// storage k' -> source k for the E pair-packing permutation:
// k' = 32a + 2r + nb  <->  k = 32a + 16nb + r
__device__ __forceinline__ int kperm(int kp) {
    return (kp & ~31) | ((kp & 1) << 4) | ((kp & 31) >> 1);
}

// ---- weight prep (unchanged) ----
__global__ __launch_bounds__(256) void prep_k(
    const float* __restrict__ We0, const float* __restrict__ Ws0,
    const float* __restrict__ We,  const float* __restrict__ Ws,
    const float* __restrict__ We2, const float* __restrict__ Wd,
    ushort* __restrict__ wbuf, float* __restrict__ wdtf)
{
    int idx = blockIdx.x * 256 + threadIdx.x;
    if (idx >= 98944) return;
    if (idx >= 98304) {
        int i = idx - 98304;
        wdtf[i] = Wd[(i & 127) * 5 + (i >> 7)];
        return;
    }
    float v;
    if (idx < 16384) {
        int n = idx >> 7, k = idx & 127;
        v = (k < 120) ? We0[k * 128 + n] : 0.f;
    } else if (idx < 24576) {
        int i = idx - 16384;
        int n = i >> 7, k = kperm(i & 127);
        v = Ws0[k * 64 + n];
    } else if (idx < 90112) {
        int i = idx - 24576;
        int l = i >> 14, j = i & 16383;
        if (j < 8192) { int n = j >> 6, k = j & 63; v = We[l * 8192 + k * 128 + n]; }
        else { int j2 = j - 8192; int n = j2 >> 7, k = kperm(j2 & 127); v = Ws[l * 8192 + k * 64 + n]; }
    } else {
        int i = idx - 90112;
        int n = i >> 6, k = i & 63;
        v = We2[k * 128 + n];
    }
    wbuf[idx] = f2b(v);
}

// ---- unit 0: 128-row straight-line, single-region X->E->Z per-row alias ----
// r16 form verbatim: (256,4), bE held across halves, batched a[] reads.
// LDS: one region [139][256B] = 35584 B -> 4 blocks/CU.
__global__ __launch_bounds__(256, 4) void unit0_big(
    const float* __restrict__ in, const ushort* __restrict__ WeT,
    const float* __restrict__ be, const ushort* __restrict__ WsT,
    const float* __restrict__ wl, const float* __restrict__ wr,
    ushort* __restrict__ Hout)
{
    __shared__ char smA[139 * 256];

    const int tid = threadIdx.x;
    const int s   = blockIdx.y;
    const int t0  = blockIdx.x * 128;
    const int ln  = tid & 63;
    const int w   = tid >> 6;
    const int lr  = ln & 15;
    const int lg  = ln >> 4;

    // ---- stage X rows 0..138 (t = t0-10+row); invalid/pad slots write zero ----
    {
        const int bq = s >> 2, cq = s & 3;
        for (int i = tid; i < 139 * 16; i += 256) {
            int r = i >> 4, s16 = i & 15;
            int t = t0 - 10 + r;
            float4 v0 = make_float4(0.f, 0.f, 0.f, 0.f), v1 = v0;
            if (t >= 0 && t < TLEN && s16 < 15) {
                int fb = ((bq * TLEN + t) * 4 + cq) * 120 + s16 * 8;
                v0 = *reinterpret_cast<const float4*>(in + fb);
                v1 = *reinterpret_cast<const float4*>(in + fb + 4);
            }
            uint4 p;
            p.x = cvtpk(v0.x, v0.y); p.y = cvtpk(v0.z, v0.w);
            p.z = cvtpk(v1.x, v1.y); p.w = cvtpk(v1.z, v1.w);
            int off = (r * 256 + s16 * 16) ^ ((r & 15) << 4);
            *reinterpret_cast<uint4*>(smA + off) = p;
        }
    }
    __syncthreads();

    // B-fragments live across both expand halves (r16 form)
    bf16x8 bE[2][4];
#pragma unroll
    for (int nt = 0; nt < 2; ++nt)
#pragma unroll
        for (int kc = 0; kc < 4; ++kc) {
            int n = w * 32 + nt * 16 + lr;
            bE[nt][kc] = *reinterpret_cast<const bf16x8*>(
                WeT + n * 128 + kc * 32 + lg * 8);
        }
    const float b0 = be[w * 32 + lr];
    const float b1 = be[w * 32 + 16 + lr];

    // ---- expand half A: mt 0..4 (X rows 0..79) ----
    {
        f32x4 accE[5][2];
#pragma unroll
        for (int mt = 0; mt < 5; ++mt)
#pragma unroll
            for (int nt = 0; nt < 2; ++nt) accE[mt][nt] = (f32x4){0.f, 0.f, 0.f, 0.f};
        __builtin_amdgcn_s_setprio(1);
#pragma unroll
        for (int kc = 0; kc < 4; ++kc) {
            bf16x8 a[5];
#pragma unroll
            for (int mt = 0; mt < 5; ++mt) {
                int row = mt * 16 + lr;
                int off = (row * 256 + kc * 64 + lg * 16) ^ ((row & 15) << 4);
                a[mt] = *reinterpret_cast<const bf16x8*>(smA + off);
            }
#pragma unroll
            for (int mt = 0; mt < 5; ++mt)
#pragma unroll
                for (int nt = 0; nt < 2; ++nt)
                    accE[mt][nt] = __builtin_amdgcn_mfma_f32_16x16x32_bf16(
                        a[mt], bE[nt][kc], accE[mt][nt], 0, 0, 0);
        }
        __builtin_amdgcn_s_setprio(0);
        __syncthreads();   // ALL waves done reading X rows 0..79
        // E rows 0..79 overwrite X rows 0..79 (per-row alias)
#pragma unroll
        for (int mt = 0; mt < 5; ++mt)
#pragma unroll
            for (int q = 0; q < 4; ++q) {
                int row = mt * 16 + lg * 4 + q;
                float v0 = fmaxf(accE[mt][0][q] + b0, 0.f);
                float v1 = fmaxf(accE[mt][1][q] + b1, 0.f);
                int off = (row * 256 + w * 64 + lr * 4) ^ ((row & 15) << 4);
                *reinterpret_cast<unsigned*>(smA + off) = cvtpk(v0, v1);
            }
    }

    // ---- expand half B: mt 5..8 (X rows 80..138, untouched; guard <139) ----
    {
        f32x4 accE[4][2];
#pragma unroll
        for (int mt = 0; mt < 4; ++mt)
#pragma unroll
            for (int nt = 0; nt < 2; ++nt) accE[mt][nt] = (f32x4){0.f, 0.f, 0.f, 0.f};
        bf16x8 zv = {0, 0, 0, 0, 0, 0, 0, 0};
        __builtin_amdgcn_s_setprio(1);
#pragma unroll
        for (int kc = 0; kc < 4; ++kc) {
            bf16x8 a[4];
#pragma unroll
            for (int mtl = 0; mtl < 4; ++mtl) {
                int row = (5 + mtl) * 16 + lr;
                int off = (row * 256 + kc * 64 + lg * 16) ^ ((row & 15) << 4);
                a[mtl] = (row < 139) ? *reinterpret_cast<const bf16x8*>(smA + off) : zv;
            }
#pragma unroll
            for (int mtl = 0; mtl < 4; ++mtl)
#pragma unroll
                for (int nt = 0; nt < 2; ++nt)
                    accE[mtl][nt] = __builtin_amdgcn_mfma_f32_16x16x32_bf16(
                        a[mtl], bE[nt][kc], accE[mtl][nt], 0, 0, 0);
        }
        __builtin_amdgcn_s_setprio(0);
        __syncthreads();   // ALL waves done reading X rows 80..138
#pragma unroll
        for (int mtl = 0; mtl < 4; ++mtl)
#pragma unroll
            for (int q = 0; q < 4; ++q) {
                int row = (5 + mtl) * 16 + lg * 4 + q;
                if (row < 139) {
                    float v0 = fmaxf(accE[mtl][0][q] + b0, 0.f);
                    float v1 = fmaxf(accE[mtl][1][q] + b1, 0.f);
                    int off = (row * 256 + w * 64 + lr * 4) ^ ((row & 15) << 4);
                    *reinterpret_cast<unsigned*>(smA + off) = cvtpk(v0, v1);
                }
            }
    }
    __syncthreads();   // all E visible

    // ---- shrink: Z[139][64] = E @ WsT_perm; wave w: cols w*16..+16 ----
    {
        bf16x8 bS[4];
#pragma unroll
        for (int kc = 0; kc < 4; ++kc) {
            int n = w * 16 + lr;
            bS[kc] = *reinterpret_cast<const bf16x8*>(WsT + n * 128 + kc * 32 + lg * 8);
        }
        f32x4 accS[9];
#pragma unroll
        for (int mt = 0; mt < 9; ++mt) accS[mt] = (f32x4){0.f, 0.f, 0.f, 0.f};
        bf16x8 zv = {0, 0, 0, 0, 0, 0, 0, 0};
        __builtin_amdgcn_s_setprio(1);
#pragma unroll
        for (int kc = 0; kc < 4; ++kc) {
#pragma unroll
            for (int mt = 0; mt < 8; ++mt) {
                int row = mt * 16 + lr;
                int off = (row * 256 + kc * 64 + lg * 16) ^ ((row & 15) << 4);
                bf16x8 a = *reinterpret_cast<const bf16x8*>(smA + off);
                accS[mt] = __builtin_amdgcn_mfma_f32_16x16x32_bf16(
                    a, bS[kc], accS[mt], 0, 0, 0);
            }
            {   // mt = 8 guarded
                int row = 128 + lr;
                int off = (row * 256 + kc * 64 + lg * 16) ^ ((row & 15) << 4);
                bf16x8 a = (row < 139) ? *reinterpret_cast<const bf16x8*>(smA + off) : zv;
                accS[8] = __builtin_amdgcn_mfma_f32_16x16x32_bf16(
                    a, bS[kc], accS[8], 0, 0, 0);
            }
        }
        __builtin_amdgcn_s_setprio(0);
        __syncthreads();   // all E reads done (Z aliases per-row)
#pragma unroll
        for (int mt = 0; mt < 9; ++mt)
#pragma unroll
            for (int q = 0; q < 4; ++q) {
                int row = mt * 16 + lg * 4 + q;
                if (row < 139) {
                    int off = (row * 256 + (w * 16 + lr) * 4) ^ ((row & 15) << 3);
                    *reinterpret_cast<float*>(smA + off) = accS[mt][q];
                }
            }
    }
    __syncthreads();

    // ---- FSMN epilogue: 2 adjacent d per thread, 16 rows each (no residual) ----
    {
        const int dp = (tid & 31) * 2;
        const int r0 = (tid >> 5) * 16;
        f32x2 wl2[10];
#pragma unroll
        for (int k = 0; k < 10; ++k)
            wl2[k] = *reinterpret_cast<const f32x2*>(wl + k * 64 + dp);
        f32x2 wr2 = *reinterpret_cast<const f32x2*>(wr + dp);

        f32x2 zw[11];
#pragma unroll
        for (int j = 0; j < 11; ++j) {
            int tt = t0 + r0 - 9 + j;
            int r  = r0 + 1 + j;
            zw[j] = (tt >= 0 && tt < TLEN)
                  ? *reinterpret_cast<const f32x2*>(
                        smA + ((r * 256 + dp * 4) ^ ((r & 15) << 3)))
                  : (f32x2){0.f, 0.f};
        }
#pragma unroll
        for (int i = 0; i < 16; ++i) {
            int ro = r0 + i, t = t0 + ro;
            f32x2 acc = zw[9];
#pragma unroll
            for (int k = 0; k < 10; ++k) acc = pkfma(wl2[k], zw[k], acc);
            acc = pkfma(wr2, zw[10], acc);
            *reinterpret_cast<unsigned*>(
                Hout + (size_t)(s * TLEN + t) * 64 + dp) = cvtpk(acc[0], acc[1]);
            if (i < 15) {
#pragma unroll
                for (int j = 0; j < 10; ++j) zw[j] = zw[j + 1];
                int tt = t + 2;
                int r  = ro + 12;
                zw[10] = (tt < TLEN)
                       ? *reinterpret_cast<const f32x2*>(
                             smA + ((r * 256 + dp * 4) ^ ((r & 15) << 3)))
                       : (f32x2){0.f, 0.f};
            }
        }
    }
}

// ---- units 1-4: 128-row straight-line tile (r15, unchanged) ----
__global__ __launch_bounds__(256, 3) void unit14_big(
    const ushort* __restrict__ Hin, const ushort* __restrict__ WeT,
    const float* __restrict__ be, const ushort* __restrict__ WsT,
    const float* __restrict__ wl, const float* __restrict__ wr,
    ushort* __restrict__ Hout)
{
    __shared__ char smraw[17792 + 35584];
    char* smA = smraw;
    char* smB = smraw + 17792;

    const int tid = threadIdx.x;
    const int s   = blockIdx.y;
    const int t0  = blockIdx.x * 128;
    const int ln  = tid & 63;
    const int w   = tid >> 6;
    const int lr  = ln & 15;
    const int lg  = ln >> 4;

    {
        bf16x8 zv = {0, 0, 0, 0, 0, 0, 0, 0};
        if (t0 == 0)
            for (int i = tid; i < 80; i += 256)
                *reinterpret_cast<bf16x8*>(smA + i * 16) = zv;
        if (t0 == TLEN - 128 && tid < 8)
            *reinterpret_cast<bf16x8*>(smA + (138 * 8 + tid) * 16) = zv;
#pragma unroll
        for (int it = 0; it < 5; ++it) {
            int r0s = it * 32 + w * 8;
            if (r0s < 139) {
                int row = r0s + (ln >> 3);
                int t   = t0 - 10 + row;
                int sslot = (ln & 7) ^ (row & 7);
                if (row < 139 && t >= 0 && t < TLEN)
                    gload16(smA + r0s * 128,
                            Hin + (size_t)(s * TLEN + t) * 64 + sslot * 8);
            }
        }
    }
    __syncthreads();

    {
        bf16x8 bE[2][2];
#pragma unroll
        for (int nt = 0; nt < 2; ++nt)
#pragma unroll
            for (int kc = 0; kc < 2; ++kc) {
                int n = w * 32 + nt * 16 + lr;
                bE[nt][kc] = *reinterpret_cast<const bf16x8*>(
                    WeT + n * 64 + kc * 32 + lg * 8);
            }
        f32x4 accE[5][2];
#pragma unroll
        for (int mt = 0; mt < 5; ++mt)
#pragma unroll
            for (int nt = 0; nt < 2; ++nt) accE[mt][nt] = (f32x4){0.f, 0.f, 0.f, 0.f};
        __builtin_amdgcn_s_setprio(1);
#pragma unroll
        for (int kc = 0; kc < 2; ++kc) {
            bf16x8 a[5];
#pragma unroll
            for (int mt = 0; mt < 5; ++mt) {
                int row = mt * 16 + lr;
                int off = (row * 128 + kc * 64 + lg * 16) ^ ((row & 7) << 4);
                a[mt] = *reinterpret_cast<const bf16x8*>(smA + off);
            }
#pragma unroll
            for (int mt = 0; mt < 5; ++mt)
#pragma unroll
                for (int nt = 0; nt < 2; ++nt)
                    accE[mt][nt] = __builtin_amdgcn_mfma_f32_16x16x32_bf16(
                        a[mt], bE[nt][kc], accE[mt][nt], 0, 0, 0);
        }
        __builtin_amdgcn_s_setprio(0);
        float b0 = be[w * 32 + lr];
        float b1 = be[w * 32 + 16 + lr];
#pragma unroll
        for (int mt = 0; mt < 5; ++mt)
#pragma unroll
            for (int q = 0; q < 4; ++q) {
                int row = mt * 16 + lg * 4 + q;
                float v0 = fmaxf(accE[mt][0][q] + b0, 0.f);
                float v1 = fmaxf(accE[mt][1][q] + b1, 0.f);
                int off = (row * 256 + w * 64 + lr * 4) ^ ((row & 15) << 4);
                *reinterpret_cast<unsigned*>(smB + off) = cvtpk(v0, v1);
            }
    }
    {
        bf16x8 bE[2][2];
#pragma unroll
        for (int nt = 0; nt < 2; ++nt)
#pragma unroll
            for (int kc = 0; kc < 2; ++kc) {
                int n = w * 32 + nt * 16 + lr;
                bE[nt][kc] = *reinterpret_cast<const bf16x8*>(
                    WeT + n * 64 + kc * 32 + lg * 8);
            }
        f32x4 accE[4][2];
#pragma unroll
        for (int mt = 0; mt < 4; ++mt)
#pragma unroll
            for (int nt = 0; nt < 2; ++nt) accE[mt][nt] = (f32x4){0.f, 0.f, 0.f, 0.f};
        bf16x8 zv = {0, 0, 0, 0, 0, 0, 0, 0};
        __builtin_amdgcn_s_setprio(1);
#pragma unroll
        for (int kc = 0; kc < 2; ++kc) {
            bf16x8 a[4];
#pragma unroll
            for (int mtl = 0; mtl < 4; ++mtl) {
                int row = (5 + mtl) * 16 + lr;
                int off = (row * 128 + kc * 64 + lg * 16) ^ ((row & 7) << 4);
                a[mtl] = (row < 139) ? *reinterpret_cast<const bf16x8*>(smA + off) : zv;
            }
#pragma unroll
            for (int mtl = 0; mtl < 4; ++mtl)
#pragma unroll
                for (int nt = 0; nt < 2; ++nt)
                    accE[mtl][nt] = __builtin_amdgcn_mfma_f32_16x16x32_bf16(
                        a[mtl], bE[nt][kc], accE[mtl][nt], 0, 0, 0);
        }
        __builtin_amdgcn_s_setprio(0);
        float b0 = be[w * 32 + lr];
        float b1 = be[w * 32 + 16 + lr];
#pragma unroll
        for (int mtl = 0; mtl < 4; ++mtl)
#pragma unroll
            for (int q = 0; q < 4; ++q) {
                int row = (5 + mtl) * 16 + lg * 4 + q;
                if (row < 139) {
                    float v0 = fmaxf(accE[mtl][0][q] + b0, 0.f);
                    float v1 = fmaxf(accE[mtl][1][q] + b1, 0.f);
                    int off = (row * 256 + w * 64 + lr * 4) ^ ((row & 15) << 4);
                    *reinterpret_cast<unsigned*>(smB + off) = cvtpk(v0, v1);
                }
            }
    }
    __syncthreads();

    {
        bf16x8 bS[4];
#pragma unroll
        for (int kc = 0; kc < 4; ++kc) {
            int n = w * 16 + lr;
            bS[kc] = *reinterpret_cast<const bf16x8*>(WsT + n * 128 + kc * 32 + lg * 8);
        }
        f32x4 accS[9];
#pragma unroll
        for (int mt = 0; mt < 9; ++mt) accS[mt] = (f32x4){0.f, 0.f, 0.f, 0.f};
        bf16x8 zv = {0, 0, 0, 0, 0, 0, 0, 0};
        __builtin_amdgcn_s_setprio(1);
#pragma unroll
        for (int kc = 0; kc < 4; ++kc) {
#pragma unroll
            for (int mt = 0; mt < 8; ++mt) {
                int row = mt * 16 + lr;
                int off = (row * 256 + kc * 64 + lg * 16) ^ ((row & 15) << 4);
                bf16x8 a = *reinterpret_cast<const bf16x8*>(smB + off);
                accS[mt] = __builtin_amdgcn_mfma_f32_16x16x32_bf16(
                    a, bS[kc], accS[mt], 0, 0, 0);
            }
            {
                int row = 128 + lr;
                int off = (row * 256 + kc * 64 + lg * 16) ^ ((row & 15) << 4);
                bf16x8 a = (row < 139) ? *reinterpret_cast<const bf16x8*>(smB + off) : zv;
                accS[8] = __builtin_amdgcn_mfma_f32_16x16x32_bf16(
                    a, bS[kc], accS[8], 0, 0, 0);
            }
        }
        __builtin_amdgcn_s_setprio(0);
        __syncthreads();
#pragma unroll
        for (int mt = 0; mt < 9; ++mt)
#pragma unroll
            for (int q = 0; q < 4; ++q) {
                int row = mt * 16 + lg * 4 + q;
                if (row < 139) {
                    int off = (row * 256 + (w * 16 + lr) * 4) ^ ((row & 15) << 3);
                    *reinterpret_cast<float*>(smB + off) = accS[mt][q];
                }
            }
    }
    __syncthreads();

    {
        const int dp = (tid & 31) * 2;
        const int r0 = (tid >> 5) * 16;
        f32x2 wl2[10];
#pragma unroll
        for (int k = 0; k < 10; ++k)
            wl2[k] = *reinterpret_cast<const f32x2*>(wl + k * 64 + dp);
        f32x2 wr2 = *reinterpret_cast<const f32x2*>(wr + dp);

        f32x2 zw[11];
#pragma unroll
        for (int j = 0; j < 11; ++j) {
            int tt = t0 + r0 - 9 + j;
            int r  = r0 + 1 + j;
            zw[j] = (tt >= 0 && tt < TLEN)
                  ? *reinterpret_cast<const f32x2*>(
                        smB + ((r * 256 + dp * 4) ^ ((r & 15) << 3)))
                  : (f32x2){0.f, 0.f};
        }
#pragma unroll
        for (int i = 0; i < 16; ++i) {
            int ro = r0 + i, t = t0 + ro;
            f32x2 acc = zw[9];
#pragma unroll
            for (int k = 0; k < 10; ++k) acc = pkfma(wl2[k], zw[k], acc);
            acc = pkfma(wr2, zw[10], acc);
            int rowX = ro + 10;
            ushort2 h = *reinterpret_cast<const ushort2*>(
                smA + ((rowX * 128 + dp * 2) ^ ((rowX & 7) << 4)));
            float a0 = acc[0] + b2f(h.x);
            float a1 = acc[1] + b2f(h.y);
            *reinterpret_cast<unsigned*>(
                Hout + (size_t)(s * TLEN + t) * 64 + dp) = cvtpk(a0, a1);
            if (i < 15) {
#pragma unroll
                for (int j = 0; j < 10; ++j) zw[j] = zw[j + 1];
                int tt = t + 2;
                int r  = ro + 12;
                zw[10] = (tt < TLEN)
                       ? *reinterpret_cast<const f32x2*>(
                             smB + ((r * 256 + dp * 4) ^ ((r & 15) << 3)))
                       : (f32x2){0.f, 0.f};
            }
        }
    }
}

// ---- final (unchanged) ----
__global__ __launch_bounds__(256) void final_mfma(
    const ushort* __restrict__ H, const ushort* __restrict__ We2T,
    const float* __restrict__ be2, const float* __restrict__ WdT,
    const float* __restrict__ bd, float* __restrict__ out)
{
    __shared__ char smA[64 * 128];
    __shared__ float Ml[16][132];
    const int tid = threadIdx.x;
    const int ln  = tid & 63;
    const int w   = tid >> 6;
    const int lr  = ln & 15;
    const int lg  = ln >> 4;
    const int b   = blockIdx.x >> 7;
    const int t0  = (blockIdx.x & 127) * 16;

#pragma unroll
    for (int it = 0; it < 2; ++it) {
        int r0 = w * 16 + it * 8;
        int tl = it * 8 + (ln >> 3);
        int m  = r0 + (ln >> 3);
        int sslot = (ln & 7) ^ (m & 7);
        gload16(smA + r0 * 128,
                H + (size_t)((b * 4 + w) * TLEN + t0 + tl) * 64 + sslot * 8);
    }
    __syncthreads();

    {
        bf16x8 bW[2][2];
#pragma unroll
        for (int nt = 0; nt < 2; ++nt)
#pragma unroll
            for (int kc = 0; kc < 2; ++kc) {
                int n = w * 32 + nt * 16 + lr;
                bW[nt][kc] = *reinterpret_cast<const bf16x8*>(
                    We2T + n * 64 + kc * 32 + lg * 8);
            }
        f32x4 acc[4][2];
#pragma unroll
        for (int mt = 0; mt < 4; ++mt)
#pragma unroll
            for (int nt = 0; nt < 2; ++nt) acc[mt][nt] = (f32x4){0.f, 0.f, 0.f, 0.f};
        __builtin_amdgcn_s_setprio(1);
#pragma unroll
        for (int kc = 0; kc < 2; ++kc) {
            bf16x8 a[4];
#pragma unroll
            for (int mt = 0; mt < 4; ++mt) {
                int m = mt * 16 + lr;
                int off = (m * 128 + kc * 64 + lg * 16) ^ ((m & 7) << 4);
                a[mt] = *reinterpret_cast<const bf16x8*>(smA + off);
            }
#pragma unroll
            for (int mt = 0; mt < 4; ++mt)
#pragma unroll
                for (int nt = 0; nt < 2; ++nt)
                    acc[mt][nt] = __builtin_amdgcn_mfma_f32_16x16x32_bf16(
                        a[mt], bW[nt][kc], acc[mt][nt], 0, 0, 0);
        }
        __builtin_amdgcn_s_setprio(0);
#pragma unroll
        for (int nt = 0; nt < 2; ++nt) {
            float bb = be2[w * 32 + nt * 16 + lr];
#pragma unroll
            for (int q = 0; q < 4; ++q) {
                float m01 = fmaxf(acc[0][nt][q], acc[1][nt][q]);
                float m23 = fmaxf(acc[2][nt][q], acc[3][nt][q]);
                Ml[lg * 4 + q][w * 32 + nt * 16 + lr] =
                    fmaxf(fmaxf(m01, m23) + bb, 0.f);
            }
        }
    }
    __syncthreads();

    if (tid < 80) {
        int t = tid / 5, q = tid - t * 5;
        const float4* wq = reinterpret_cast<const float4*>(WdT + q * 128);
        const float4* mq = reinterpret_cast<const float4*>(&Ml[t][0]);
        float s0 = 0.f, s1 = 0.f, s2 = 0.f, s3 = 0.f;
#pragma unroll 4
        for (int j = 0; j < 32; ++j) {
            float4 m = mq[j], wv = wq[j];
            s0 += m.x * wv.x; s1 += m.y * wv.y;
            s2 += m.z * wv.z; s3 += m.w * wv.w;
        }
        out[(size_t)(b * TLEN + t0 + t) * 5 + q] = s0 + s1 + s2 + s3 + bd[q];
    }
}

extern "C" void kernel_launch(void* const* d_in, const int* in_sizes, int n_in,
                              void* d_out, int out_size, void* d_ws, size_t ws_size,
                              hipStream_t stream) {
    const float* x   = (const float*)d_in[0];
    const float* We0 = (const float*)d_in[1];
    const float* be0 = (const float*)d_in[2];
    const float* Ws0 = (const float*)d_in[3];
    const float* wl0 = (const float*)d_in[4];
    const float* wr0 = (const float*)d_in[5];
    const float* We  = (const float*)d_in[6];
    const float* be  = (const float*)d_in[7];
    const float* Ws  = (const float*)d_in[8];
    const float* wl  = (const float*)d_in[9];
    const float* wr  = (const float*)d_in[10];
    const float* We2 = (const float*)d_in[11];
    const float* be2 = (const float*)d_in[12];
    const float* Wd  = (const float*)d_in[13];
    const float* bd  = (const float*)d_in[14];

    ushort* H0 = (ushort*)d_ws;                               // 33.5 MB
    ushort* H1 = H0 + (size_t)SEQS * TLEN * 64;               // 33.5 MB
    ushort* wbuf = H1 + (size_t)SEQS * TLEN * 64;             // 192 KB
    float* wdtf = (float*)(wbuf + 98304);                     // 2.5 KB

    prep_k<<<387, 256, 0, stream>>>(We0, Ws0, We, Ws, We2, Wd, wbuf, wdtf);

    unit0_big<<<dim3(TLEN / 128, SEQS), 256, 0, stream>>>(
        x, wbuf, be0, wbuf + 16384, wl0, wr0, H0);

    ushort* cur = H0;
    ushort* nxt = H1;
    for (int l = 0; l < 4; ++l) {
        const ushort* WeTl = wbuf + 24576 + l * 16384;
        const ushort* WsTl = WeTl + 8192;
        unit14_big<<<dim3(TLEN / 128, SEQS), 256, 0, stream>>>(
            cur, WeTl, be + l * 128, WsTl, wl + l * 640, wr + l * 64, nxt);
        ushort* tmp = cur; cur = nxt; nxt = tmp;
    }
    // after 4 swaps cur == H0

    final_mfma<<<32 * 128, 256, 0, stream>>>(cur, wbuf + 90112, be2, wdtf, bd,
                                             (float*)d_out);
}

// Round 21
// 203.439 us; speedup vs baseline: 1.0619x; 1.0342x over previous
//
#include <hip/hip_runtime.h>
#include <hip/hip_bf16.h>

// FSMNSeleNetV3 — round 21: unit14_big to 4 blocks/CU via X/E region aliasing.
//   Occupancy ledger (unit0, r16-r20): 4 blk/CU > 3 wv > 2 wv, monotone.
//   unit14 was the last kernel at 3 blk (LDS 53376). New layout (35584 B):
//     E [139][256B] @0 ; X [139][128B] @17792.
//     halfA E-store (bytes 0..20479) clobbers only X rows 0..20 (dead);
//     halfB reads X rows 80..138 @28032+ (disjoint from halfA store);
//     halfB E-store behind a barrier clobbers the rest. 6 barriers (+2).
//   Residual returns to a global re-read (ping-pong safe; measured ~2 us
//   cost at r4<->r7 vs ~4 us/kernel occupancy gain at unit0).
//   (256,4); peak live ~40 AGPR + ~51 arch << 128 -> no-spill predicted.
//   unit0_big / final / prep unchanged from r20 (210.4 us).
// d_ws: H0 (33.5MB) + H1 (33.5MB) + wbuf (192KB bf16 weights) + WdT (2.5KB f32).

#define TLEN 2048
#define SEQS 128

typedef __attribute__((ext_vector_type(8))) short bf16x8;
typedef __attribute__((ext_vector_type(4))) float f32x4;
typedef __attribute__((ext_vector_type(2))) float f32x2;

__device__ __forceinline__ ushort f2b(float f) {
    unsigned u = __builtin_bit_cast(unsigned, f);
    return (ushort)((u + 0x7fffu + ((u >> 16) & 1u)) >> 16);  // RNE
}
__device__ __forceinline__ float b2f(ushort u) {
    unsigned v = ((unsigned)u) << 16;
    return __builtin_bit_cast(float, v);
}
__device__ __forceinline__ unsigned cvtpk(float lo, float hi) {  // RNE pack
    unsigned r;
    asm("v_cvt_pk_bf16_f32 %0, %1, %2" : "=v"(r) : "v"(lo), "v"(hi));
    return r;
}
__device__ __forceinline__ f32x2 pkfma(f32x2 a, f32x2 b, f32x2 c) {
    f32x2 d;
    asm("v_pk_fma_f32 %0, %1, %2, %3" : "=v"(d) : "v"(a), "v"(b), "v"(c));
    return d;
}
__device__ __forceinline__ void gload16(void* lds, const void* g) {
    __builtin_amdgcn_global_load_lds(
        (const __attribute__((address_space(1))) unsigned*)g,
        (__attribute__((address_space(3))) unsigned*)lds, 16, 0, 0);
}

// storage k' -> source k for the E pair-packing permutation:
// k' = 32a + 2r + nb  <->  k = 32a + 16nb + r
__device__ __forceinline__ int kperm(int kp) {
    return (kp & ~31) | ((kp & 1) << 4) | ((kp & 31) >> 1);
}

// ---- weight prep (unchanged) ----
__global__ __launch_bounds__(256) void prep_k(
    const float* __restrict__ We0, const float* __restrict__ Ws0,
    const float* __restrict__ We,  const float* __restrict__ Ws,
    const float* __restrict__ We2, const float* __restrict__ Wd,
    ushort* __restrict__ wbuf, float* __restrict__ wdtf)
{
    int idx = blockIdx.x * 256 + threadIdx.x;
    if (idx >= 98944) return;
    if (idx >= 98304) {
        int i = idx - 98304;
        wdtf[i] = Wd[(i & 127) * 5 + (i >> 7)];
        return;
    }
    float v;
    if (idx < 16384) {
        int n = idx >> 7, k = idx & 127;
        v = (k < 120) ? We0[k * 128 + n] : 0.f;
    } else if (idx < 24576) {
        int i = idx - 16384;
        int n = i >> 7, k = kperm(i & 127);
        v = Ws0[k * 64 + n];
    } else if (idx < 90112) {
        int i = idx - 24576;
        int l = i >> 14, j = i & 16383;
        if (j < 8192) { int n = j >> 6, k = j & 63; v = We[l * 8192 + k * 128 + n]; }
        else { int j2 = j - 8192; int n = j2 >> 7, k = kperm(j2 & 127); v = Ws[l * 8192 + k * 64 + n]; }
    } else {
        int i = idx - 90112;
        int n = i >> 6, k = i & 63;
        v = We2[k * 128 + n];
    }
    wbuf[idx] = f2b(v);
}

// ---- unit 0: r16/r20 form verbatim (best) ----
__global__ __launch_bounds__(256, 4) void unit0_big(
    const float* __restrict__ in, const ushort* __restrict__ WeT,
    const float* __restrict__ be, const ushort* __restrict__ WsT,
    const float* __restrict__ wl, const float* __restrict__ wr,
    ushort* __restrict__ Hout)
{
    __shared__ char smA[139 * 256];

    const int tid = threadIdx.x;
    const int s   = blockIdx.y;
    const int t0  = blockIdx.x * 128;
    const int ln  = tid & 63;
    const int w   = tid >> 6;
    const int lr  = ln & 15;
    const int lg  = ln >> 4;

    {
        const int bq = s >> 2, cq = s & 3;
        for (int i = tid; i < 139 * 16; i += 256) {
            int r = i >> 4, s16 = i & 15;
            int t = t0 - 10 + r;
            float4 v0 = make_float4(0.f, 0.f, 0.f, 0.f), v1 = v0;
            if (t >= 0 && t < TLEN && s16 < 15) {
                int fb = ((bq * TLEN + t) * 4 + cq) * 120 + s16 * 8;
                v0 = *reinterpret_cast<const float4*>(in + fb);
                v1 = *reinterpret_cast<const float4*>(in + fb + 4);
            }
            uint4 p;
            p.x = cvtpk(v0.x, v0.y); p.y = cvtpk(v0.z, v0.w);
            p.z = cvtpk(v1.x, v1.y); p.w = cvtpk(v1.z, v1.w);
            int off = (r * 256 + s16 * 16) ^ ((r & 15) << 4);
            *reinterpret_cast<uint4*>(smA + off) = p;
        }
    }
    __syncthreads();

    bf16x8 bE[2][4];
#pragma unroll
    for (int nt = 0; nt < 2; ++nt)
#pragma unroll
        for (int kc = 0; kc < 4; ++kc) {
            int n = w * 32 + nt * 16 + lr;
            bE[nt][kc] = *reinterpret_cast<const bf16x8*>(
                WeT + n * 128 + kc * 32 + lg * 8);
        }
    const float b0 = be[w * 32 + lr];
    const float b1 = be[w * 32 + 16 + lr];

    {
        f32x4 accE[5][2];
#pragma unroll
        for (int mt = 0; mt < 5; ++mt)
#pragma unroll
            for (int nt = 0; nt < 2; ++nt) accE[mt][nt] = (f32x4){0.f, 0.f, 0.f, 0.f};
        __builtin_amdgcn_s_setprio(1);
#pragma unroll
        for (int kc = 0; kc < 4; ++kc) {
            bf16x8 a[5];
#pragma unroll
            for (int mt = 0; mt < 5; ++mt) {
                int row = mt * 16 + lr;
                int off = (row * 256 + kc * 64 + lg * 16) ^ ((row & 15) << 4);
                a[mt] = *reinterpret_cast<const bf16x8*>(smA + off);
            }
#pragma unroll
            for (int mt = 0; mt < 5; ++mt)
#pragma unroll
                for (int nt = 0; nt < 2; ++nt)
                    accE[mt][nt] = __builtin_amdgcn_mfma_f32_16x16x32_bf16(
                        a[mt], bE[nt][kc], accE[mt][nt], 0, 0, 0);
        }
        __builtin_amdgcn_s_setprio(0);
        __syncthreads();
#pragma unroll
        for (int mt = 0; mt < 5; ++mt)
#pragma unroll
            for (int q = 0; q < 4; ++q) {
                int row = mt * 16 + lg * 4 + q;
                float v0 = fmaxf(accE[mt][0][q] + b0, 0.f);
                float v1 = fmaxf(accE[mt][1][q] + b1, 0.f);
                int off = (row * 256 + w * 64 + lr * 4) ^ ((row & 15) << 4);
                *reinterpret_cast<unsigned*>(smA + off) = cvtpk(v0, v1);
            }
    }

    {
        f32x4 accE[4][2];
#pragma unroll
        for (int mt = 0; mt < 4; ++mt)
#pragma unroll
            for (int nt = 0; nt < 2; ++nt) accE[mt][nt] = (f32x4){0.f, 0.f, 0.f, 0.f};
        bf16x8 zv = {0, 0, 0, 0, 0, 0, 0, 0};
        __builtin_amdgcn_s_setprio(1);
#pragma unroll
        for (int kc = 0; kc < 4; ++kc) {
            bf16x8 a[4];
#pragma unroll
            for (int mtl = 0; mtl < 4; ++mtl) {
                int row = (5 + mtl) * 16 + lr;
                int off = (row * 256 + kc * 64 + lg * 16) ^ ((row & 15) << 4);
                a[mtl] = (row < 139) ? *reinterpret_cast<const bf16x8*>(smA + off) : zv;
            }
#pragma unroll
            for (int mtl = 0; mtl < 4; ++mtl)
#pragma unroll
                for (int nt = 0; nt < 2; ++nt)
                    accE[mtl][nt] = __builtin_amdgcn_mfma_f32_16x16x32_bf16(
                        a[mtl], bE[nt][kc], accE[mtl][nt], 0, 0, 0);
        }
        __builtin_amdgcn_s_setprio(0);
        __syncthreads();
#pragma unroll
        for (int mtl = 0; mtl < 4; ++mtl)
#pragma unroll
            for (int q = 0; q < 4; ++q) {
                int row = (5 + mtl) * 16 + lg * 4 + q;
                if (row < 139) {
                    float v0 = fmaxf(accE[mtl][0][q] + b0, 0.f);
                    float v1 = fmaxf(accE[mtl][1][q] + b1, 0.f);
                    int off = (row * 256 + w * 64 + lr * 4) ^ ((row & 15) << 4);
                    *reinterpret_cast<unsigned*>(smA + off) = cvtpk(v0, v1);
                }
            }
    }
    __syncthreads();

    {
        bf16x8 bS[4];
#pragma unroll
        for (int kc = 0; kc < 4; ++kc) {
            int n = w * 16 + lr;
            bS[kc] = *reinterpret_cast<const bf16x8*>(WsT + n * 128 + kc * 32 + lg * 8);
        }
        f32x4 accS[9];
#pragma unroll
        for (int mt = 0; mt < 9; ++mt) accS[mt] = (f32x4){0.f, 0.f, 0.f, 0.f};
        bf16x8 zv = {0, 0, 0, 0, 0, 0, 0, 0};
        __builtin_amdgcn_s_setprio(1);
#pragma unroll
        for (int kc = 0; kc < 4; ++kc) {
#pragma unroll
            for (int mt = 0; mt < 8; ++mt) {
                int row = mt * 16 + lr;
                int off = (row * 256 + kc * 64 + lg * 16) ^ ((row & 15) << 4);
                bf16x8 a = *reinterpret_cast<const bf16x8*>(smA + off);
                accS[mt] = __builtin_amdgcn_mfma_f32_16x16x32_bf16(
                    a, bS[kc], accS[mt], 0, 0, 0);
            }
            {
                int row = 128 + lr;
                int off = (row * 256 + kc * 64 + lg * 16) ^ ((row & 15) << 4);
                bf16x8 a = (row < 139) ? *reinterpret_cast<const bf16x8*>(smA + off) : zv;
                accS[8] = __builtin_amdgcn_mfma_f32_16x16x32_bf16(
                    a, bS[kc], accS[8], 0, 0, 0);
            }
        }
        __builtin_amdgcn_s_setprio(0);
        __syncthreads();
#pragma unroll
        for (int mt = 0; mt < 9; ++mt)
#pragma unroll
            for (int q = 0; q < 4; ++q) {
                int row = mt * 16 + lg * 4 + q;
                if (row < 139) {
                    int off = (row * 256 + (w * 16 + lr) * 4) ^ ((row & 15) << 3);
                    *reinterpret_cast<float*>(smA + off) = accS[mt][q];
                }
            }
    }
    __syncthreads();

    {
        const int dp = (tid & 31) * 2;
        const int r0 = (tid >> 5) * 16;
        f32x2 wl2[10];
#pragma unroll
        for (int k = 0; k < 10; ++k)
            wl2[k] = *reinterpret_cast<const f32x2*>(wl + k * 64 + dp);
        f32x2 wr2 = *reinterpret_cast<const f32x2*>(wr + dp);

        f32x2 zw[11];
#pragma unroll
        for (int j = 0; j < 11; ++j) {
            int tt = t0 + r0 - 9 + j;
            int r  = r0 + 1 + j;
            zw[j] = (tt >= 0 && tt < TLEN)
                  ? *reinterpret_cast<const f32x2*>(
                        smA + ((r * 256 + dp * 4) ^ ((r & 15) << 3)))
                  : (f32x2){0.f, 0.f};
        }
#pragma unroll
        for (int i = 0; i < 16; ++i) {
            int ro = r0 + i, t = t0 + ro;
            f32x2 acc = zw[9];
#pragma unroll
            for (int k = 0; k < 10; ++k) acc = pkfma(wl2[k], zw[k], acc);
            acc = pkfma(wr2, zw[10], acc);
            *reinterpret_cast<unsigned*>(
                Hout + (size_t)(s * TLEN + t) * 64 + dp) = cvtpk(acc[0], acc[1]);
            if (i < 15) {
#pragma unroll
                for (int j = 0; j < 10; ++j) zw[j] = zw[j + 1];
                int tt = t + 2;
                int r  = ro + 12;
                zw[10] = (tt < TLEN)
                       ? *reinterpret_cast<const f32x2*>(
                             smA + ((r * 256 + dp * 4) ^ ((r & 15) << 3)))
                       : (f32x2){0.f, 0.f};
            }
        }
    }
}

// ---- units 1-4: 128-row tile, X/E region-aliased (35584 B -> 4 blocks/CU) ----
// E [139][256B] @0 (swz (r&15)<<4; later Z f32 swz (r&15)<<3);
// X [139][128B] @17792 (swz (r&7)<<4). Residual re-read from global.
__global__ __launch_bounds__(256, 4) void unit14_big(
    const ushort* __restrict__ Hin, const ushort* __restrict__ WeT,
    const float* __restrict__ be, const ushort* __restrict__ WsT,
    const float* __restrict__ wl, const float* __restrict__ wr,
    ushort* __restrict__ Hout)
{
    __shared__ char smraw[35584];
    char* smE = smraw;
    char* smX = smraw + 17792;

    const int tid = threadIdx.x;
    const int s   = blockIdx.y;
    const int t0  = blockIdx.x * 128;
    const int ln  = tid & 63;
    const int w   = tid >> 6;
    const int lr  = ln & 15;
    const int lg  = ln >> 4;

    // ---- stage X rows 0..138 into smX (async DMA, src-swizzled) ----
    {
        bf16x8 zv = {0, 0, 0, 0, 0, 0, 0, 0};
        if (t0 == 0)
            for (int i = tid; i < 80; i += 256)               // rows 0..9
                *reinterpret_cast<bf16x8*>(smX + i * 16) = zv;
        if (t0 == TLEN - 128 && tid < 8)                      // row 138
            *reinterpret_cast<bf16x8*>(smX + (138 * 8 + tid) * 16) = zv;
#pragma unroll
        for (int it = 0; it < 5; ++it) {
            int r0s = it * 32 + w * 8;
            if (r0s < 139) {
                int row = r0s + (ln >> 3);
                int t   = t0 - 10 + row;
                int sslot = (ln & 7) ^ (row & 7);
                if (row < 139 && t >= 0 && t < TLEN)
                    gload16(smX + r0s * 128,
                            Hin + (size_t)(s * TLEN + t) * 64 + sslot * 8);
            }
        }
    }
    __syncthreads();

    // ---- expand half A: mt 0..4 (X rows 0..79) ----
    {
        bf16x8 bE[2][2];
#pragma unroll
        for (int nt = 0; nt < 2; ++nt)
#pragma unroll
            for (int kc = 0; kc < 2; ++kc) {
                int n = w * 32 + nt * 16 + lr;
                bE[nt][kc] = *reinterpret_cast<const bf16x8*>(
                    WeT + n * 64 + kc * 32 + lg * 8);
            }
        f32x4 accE[5][2];
#pragma unroll
        for (int mt = 0; mt < 5; ++mt)
#pragma unroll
            for (int nt = 0; nt < 2; ++nt) accE[mt][nt] = (f32x4){0.f, 0.f, 0.f, 0.f};
        __builtin_amdgcn_s_setprio(1);
#pragma unroll
        for (int kc = 0; kc < 2; ++kc) {
            bf16x8 a[5];
#pragma unroll
            for (int mt = 0; mt < 5; ++mt) {
                int row = mt * 16 + lr;
                int off = (row * 128 + kc * 64 + lg * 16) ^ ((row & 7) << 4);
                a[mt] = *reinterpret_cast<const bf16x8*>(smX + off);
            }
#pragma unroll
            for (int mt = 0; mt < 5; ++mt)
#pragma unroll
                for (int nt = 0; nt < 2; ++nt)
                    accE[mt][nt] = __builtin_amdgcn_mfma_f32_16x16x32_bf16(
                        a[mt], bE[nt][kc], accE[mt][nt], 0, 0, 0);
        }
        __builtin_amdgcn_s_setprio(0);
        __syncthreads();   // ALL waves done reading X rows 0..79
        // E rows 0..79 -> bytes 0..20479: clobbers only X rows 0..20 (dead)
        float b0 = be[w * 32 + lr];
        float b1 = be[w * 32 + 16 + lr];
#pragma unroll
        for (int mt = 0; mt < 5; ++mt)
#pragma unroll
            for (int q = 0; q < 4; ++q) {
                int row = mt * 16 + lg * 4 + q;
                float v0 = fmaxf(accE[mt][0][q] + b0, 0.f);
                float v1 = fmaxf(accE[mt][1][q] + b1, 0.f);
                int off = (row * 256 + w * 64 + lr * 4) ^ ((row & 15) << 4);
                *reinterpret_cast<unsigned*>(smE + off) = cvtpk(v0, v1);
            }
    }

    // ---- expand half B: mt 5..8 (X rows 80..138 @ bytes 28032+, untouched) ----
    {
        bf16x8 bE[2][2];
#pragma unroll
        for (int nt = 0; nt < 2; ++nt)
#pragma unroll
            for (int kc = 0; kc < 2; ++kc) {
                int n = w * 32 + nt * 16 + lr;
                bE[nt][kc] = *reinterpret_cast<const bf16x8*>(
                    WeT + n * 64 + kc * 32 + lg * 8);
            }
        f32x4 accE[4][2];
#pragma unroll
        for (int mt = 0; mt < 4; ++mt)
#pragma unroll
            for (int nt = 0; nt < 2; ++nt) accE[mt][nt] = (f32x4){0.f, 0.f, 0.f, 0.f};
        bf16x8 zv = {0, 0, 0, 0, 0, 0, 0, 0};
        __builtin_amdgcn_s_setprio(1);
#pragma unroll
        for (int kc = 0; kc < 2; ++kc) {
            bf16x8 a[4];
#pragma unroll
            for (int mtl = 0; mtl < 4; ++mtl) {
                int row = (5 + mtl) * 16 + lr;
                int off = (row * 128 + kc * 64 + lg * 16) ^ ((row & 7) << 4);
                a[mtl] = (row < 139) ? *reinterpret_cast<const bf16x8*>(smX + off) : zv;
            }
#pragma unroll
            for (int mtl = 0; mtl < 4; ++mtl)
#pragma unroll
                for (int nt = 0; nt < 2; ++nt)
                    accE[mtl][nt] = __builtin_amdgcn_mfma_f32_16x16x32_bf16(
                        a[mtl], bE[nt][kc], accE[mtl][nt], 0, 0, 0);
        }
        __builtin_amdgcn_s_setprio(0);
        __syncthreads();   // ALL waves done reading X rows 80..138
        // E rows 80..138 -> bytes 20480..35583: clobbers X rows 21..138 (dead)
        float b0 = be[w * 32 + lr];
        float b1 = be[w * 32 + 16 + lr];
#pragma unroll
        for (int mtl = 0; mtl < 4; ++mtl)
#pragma unroll
            for (int q = 0; q < 4; ++q) {
                int row = (5 + mtl) * 16 + lg * 4 + q;
                if (row < 139) {
                    float v0 = fmaxf(accE[mtl][0][q] + b0, 0.f);
                    float v1 = fmaxf(accE[mtl][1][q] + b1, 0.f);
                    int off = (row * 256 + w * 64 + lr * 4) ^ ((row & 15) << 4);
                    *reinterpret_cast<unsigned*>(smE + off) = cvtpk(v0, v1);
                }
            }
    }
    __syncthreads();   // all E visible

    // ---- shrink: Z[139][64] = E @ WsT_perm; wave w: cols w*16..+16 ----
    {
        bf16x8 bS[4];
#pragma unroll
        for (int kc = 0; kc < 4; ++kc) {
            int n = w * 16 + lr;
            bS[kc] = *reinterpret_cast<const bf16x8*>(WsT + n * 128 + kc * 32 + lg * 8);
        }
        f32x4 accS[9];
#pragma unroll
        for (int mt = 0; mt < 9; ++mt) accS[mt] = (f32x4){0.f, 0.f, 0.f, 0.f};
        bf16x8 zv = {0, 0, 0, 0, 0, 0, 0, 0};
        __builtin_amdgcn_s_setprio(1);
#pragma unroll
        for (int kc = 0; kc < 4; ++kc) {
#pragma unroll
            for (int mt = 0; mt < 8; ++mt) {
                int row = mt * 16 + lr;
                int off = (row * 256 + kc * 64 + lg * 16) ^ ((row & 15) << 4);
                bf16x8 a = *reinterpret_cast<const bf16x8*>(smE + off);
                accS[mt] = __builtin_amdgcn_mfma_f32_16x16x32_bf16(
                    a, bS[kc], accS[mt], 0, 0, 0);
            }
            {   // mt = 8 guarded
                int row = 128 + lr;
                int off = (row * 256 + kc * 64 + lg * 16) ^ ((row & 15) << 4);
                bf16x8 a = (row < 139) ? *reinterpret_cast<const bf16x8*>(smE + off) : zv;
                accS[8] = __builtin_amdgcn_mfma_f32_16x16x32_bf16(
                    a, bS[kc], accS[8], 0, 0, 0);
            }
        }
        __builtin_amdgcn_s_setprio(0);
        __syncthreads();   // all E reads done (Z aliases per-row)
#pragma unroll
        for (int mt = 0; mt < 9; ++mt)
#pragma unroll
            for (int q = 0; q < 4; ++q) {
                int row = mt * 16 + lg * 4 + q;
                if (row < 139) {
                    int off = (row * 256 + (w * 16 + lr) * 4) ^ ((row & 15) << 3);
                    *reinterpret_cast<float*>(smE + off) = accS[mt][q];
                }
            }
    }
    __syncthreads();

    // ---- FSMN epilogue: residual from GLOBAL (ping-pong safe) ----
    {
        const int dp = (tid & 31) * 2;
        const int r0 = (tid >> 5) * 16;
        f32x2 wl2[10];
#pragma unroll
        for (int k = 0; k < 10; ++k)
            wl2[k] = *reinterpret_cast<const f32x2*>(wl + k * 64 + dp);
        f32x2 wr2 = *reinterpret_cast<const f32x2*>(wr + dp);

        ushort2 rs[16];
#pragma unroll
        for (int i = 0; i < 16; ++i)
            rs[i] = *reinterpret_cast<const ushort2*>(
                Hin + (size_t)(s * TLEN + t0 + r0 + i) * 64 + dp);

        f32x2 zw[11];
#pragma unroll
        for (int j = 0; j < 11; ++j) {
            int tt = t0 + r0 - 9 + j;
            int r  = r0 + 1 + j;
            zw[j] = (tt >= 0 && tt < TLEN)
                  ? *reinterpret_cast<const f32x2*>(
                        smE + ((r * 256 + dp * 4) ^ ((r & 15) << 3)))
                  : (f32x2){0.f, 0.f};
        }
#pragma unroll
        for (int i = 0; i < 16; ++i) {
            int ro = r0 + i, t = t0 + ro;
            f32x2 acc = zw[9];
#pragma unroll
            for (int k = 0; k < 10; ++k) acc = pkfma(wl2[k], zw[k], acc);
            acc = pkfma(wr2, zw[10], acc);
            float a0 = acc[0] + b2f(rs[i].x);
            float a1 = acc[1] + b2f(rs[i].y);
            *reinterpret_cast<unsigned*>(
                Hout + (size_t)(s * TLEN + t) * 64 + dp) = cvtpk(a0, a1);
            if (i < 15) {
#pragma unroll
                for (int j = 0; j < 10; ++j) zw[j] = zw[j + 1];
                int tt = t + 2;
                int r  = ro + 12;
                zw[10] = (tt < TLEN)
                       ? *reinterpret_cast<const f32x2*>(
                             smE + ((r * 256 + dp * 4) ^ ((r & 15) << 3)))
                       : (f32x2){0.f, 0.f};
            }
        }
    }
}

// ---- final (unchanged) ----
__global__ __launch_bounds__(256) void final_mfma(
    const ushort* __restrict__ H, const ushort* __restrict__ We2T,
    const float* __restrict__ be2, const float* __restrict__ WdT,
    const float* __restrict__ bd, float* __restrict__ out)
{
    __shared__ char smA[64 * 128];
    __shared__ float Ml[16][132];
    const int tid = threadIdx.x;
    const int ln  = tid & 63;
    const int w   = tid >> 6;
    const int lr  = ln & 15;
    const int lg  = ln >> 4;
    const int b   = blockIdx.x >> 7;
    const int t0  = (blockIdx.x & 127) * 16;

#pragma unroll
    for (int it = 0; it < 2; ++it) {
        int r0 = w * 16 + it * 8;
        int tl = it * 8 + (ln >> 3);
        int m  = r0 + (ln >> 3);
        int sslot = (ln & 7) ^ (m & 7);
        gload16(smA + r0 * 128,
                H + (size_t)((b * 4 + w) * TLEN + t0 + tl) * 64 + sslot * 8);
    }
    __syncthreads();

    {
        bf16x8 bW[2][2];
#pragma unroll
        for (int nt = 0; nt < 2; ++nt)
#pragma unroll
            for (int kc = 0; kc < 2; ++kc) {
                int n = w * 32 + nt * 16 + lr;
                bW[nt][kc] = *reinterpret_cast<const bf16x8*>(
                    We2T + n * 64 + kc * 32 + lg * 8);
            }
        f32x4 acc[4][2];
#pragma unroll
        for (int mt = 0; mt < 4; ++mt)
#pragma unroll
            for (int nt = 0; nt < 2; ++nt) acc[mt][nt] = (f32x4){0.f, 0.f, 0.f, 0.f};
        __builtin_amdgcn_s_setprio(1);
#pragma unroll
        for (int kc = 0; kc < 2; ++kc) {
            bf16x8 a[4];
#pragma unroll
            for (int mt = 0; mt < 4; ++mt) {
                int m = mt * 16 + lr;
                int off = (m * 128 + kc * 64 + lg * 16) ^ ((m & 7) << 4);
                a[mt] = *reinterpret_cast<const bf16x8*>(smA + off);
            }
#pragma unroll
            for (int mt = 0; mt < 4; ++mt)
#pragma unroll
                for (int nt = 0; nt < 2; ++nt)
                    acc[mt][nt] = __builtin_amdgcn_mfma_f32_16x16x32_bf16(
                        a[mt], bW[nt][kc], acc[mt][nt], 0, 0, 0);
        }
        __builtin_amdgcn_s_setprio(0);
#pragma unroll
        for (int nt = 0; nt < 2; ++nt) {
            float bb = be2[w * 32 + nt * 16 + lr];
#pragma unroll
            for (int q = 0; q < 4; ++q) {
                float m01 = fmaxf(acc[0][nt][q], acc[1][nt][q]);
                float m23 = fmaxf(acc[2][nt][q], acc[3][nt][q]);
                Ml[lg * 4 + q][w * 32 + nt * 16 + lr] =
                    fmaxf(fmaxf(m01, m23) + bb, 0.f);
            }
        }
    }
    __syncthreads();

    if (tid < 80) {
        int t = tid / 5, q = tid - t * 5;
        const float4* wq = reinterpret_cast<const float4*>(WdT + q * 128);
        const float4* mq = reinterpret_cast<const float4*>(&Ml[t][0]);
        float s0 = 0.f, s1 = 0.f, s2 = 0.f, s3 = 0.f;
#pragma unroll 4
        for (int j = 0; j < 32; ++j) {
            float4 m = mq[j], wv = wq[j];
            s0 += m.x * wv.x; s1 += m.y * wv.y;
            s2 += m.z * wv.z; s3 += m.w * wv.w;
        }
        out[(size_t)(b * TLEN + t0 + t) * 5 + q] = s0 + s1 + s2 + s3 + bd[q];
    }
}

extern "C" void kernel_launch(void* const* d_in, const int* in_sizes, int n_in,
                              void* d_out, int out_size, void* d_ws, size_t ws_size,
                              hipStream_t stream) {
    const float* x   = (const float*)d_in[0];
    const float* We0 = (const float*)d_in[1];
    const float* be0 = (const float*)d_in[2];
    const float* Ws0 = (const float*)d_in[3];
    const float* wl0 = (const float*)d_in[4];
    const float* wr0 = (const float*)d_in[5];
    const float* We  = (const float*)d_in[6];
    const float* be  = (const float*)d_in[7];
    const float* Ws  = (const float*)d_in[8];
    const float* wl  = (const float*)d_in[9];
    const float* wr  = (const float*)d_in[10];
    const float* We2 = (const float*)d_in[11];
    const float* be2 = (const float*)d_in[12];
    const float* Wd  = (const float*)d_in[13];
    const float* bd  = (const float*)d_in[14];

    ushort* H0 = (ushort*)d_ws;                               // 33.5 MB
    ushort* H1 = H0 + (size_t)SEQS * TLEN * 64;               // 33.5 MB
    ushort* wbuf = H1 + (size_t)SEQS * TLEN * 64;             // 192 KB
    float* wdtf = (float*)(wbuf + 98304);                     // 2.5 KB

    prep_k<<<387, 256, 0, stream>>>(We0, Ws0, We, Ws, We2, Wd, wbuf, wdtf);

    unit0_big<<<dim3(TLEN / 128, SEQS), 256, 0, stream>>>(
        x, wbuf, be0, wbuf + 16384, wl0, wr0, H0);

    ushort* cur = H0;
    ushort* nxt = H1;
    for (int l = 0; l < 4; ++l) {
        const ushort* WeTl = wbuf + 24576 + l * 16384;
        const ushort* WsTl = WeTl + 8192;
        unit14_big<<<dim3(TLEN / 128, SEQS), 256, 0, stream>>>(
            cur, WeTl, be + l * 128, WsTl, wl + l * 640, wr + l * 64, nxt);
        ushort* tmp = cur; cur = nxt; nxt = tmp;
    }
    // after 4 swaps cur == H0

    final_mfma<<<32 * 128, 256, 0, stream>>>(cur, wbuf + 90112, be2, wdtf, bd,
                                             (float*)d_out);
}